// Round 7
// baseline (1193.707 us; speedup 1.0000x reference)
//
#include <hip/hip_runtime.h>
#include <hip/hip_bf16.h>

#define N_USER 50000
#define N_ITEM 30000
#define NTOT   80000
#define EMB    64
#define FAC    4
#define EDGES  1000000
#define LOG4   1.3862943611198906f
#define SB     1024
#define NBLK   79   // ceil(80000/1024)

// ws layout (float idx), total 20,000,274 floats = 80.0 MB:
//   fac   +0          5,120,000  (fp32, current-pass factor_emb for k_upd/rhn)
//   L     +5,120,000  4,000,000  (log-softmax of A, CSR position order)
//   dv0   +9,120,000    320,000  (dvinv / dval ping)
//   dv1   +9,440,000    320,000  (dvinv / dval pong)
//   rhn   +9,760,000    320,000
//   egoh  +10,080,000 2,560,000  (bf16 layer-input embeddings, 5.12M ushort)
//   fach  +12,640,000 2,560,000  (bf16 layer-output embeddings)
//   tnhh  +15,200,000 2,560,000  (bf16 tanh-normalized tails)
//   flag  +17,760,000  16
//   deg   +17,760,016  80,000 | off +17,840,016 80,001 | cur +17,920,017 80,000
//   et    +18,000,018  2,000,000 (int2 per CSR pos: {h,t}; 8B-aligned)
//   bsum  +20,000,018  128 | bbase +20,000,146 128

__device__ inline float bf2f(unsigned short u) {
    return __uint_as_float(((unsigned int)u) << 16);
}
__device__ inline unsigned short f2bf(float f) {
    unsigned int x = __float_as_uint(f);
    x += 0x7FFFu + ((x >> 16) & 1u);       // round-to-nearest-even
    return (unsigned short)(x >> 16);
}
__device__ inline void unpack2(unsigned int u, float& a, float& b) {
    a = __uint_as_float(u << 16);
    b = __uint_as_float(u & 0xFFFF0000u);
}

// ---- input dtype detector (fp32 read-as-bf16 shows inf/NaN bit patterns) ----
__global__ void k_detect(const unsigned short* __restrict__ raw, int* __restrict__ flag) {
    __shared__ int s;
    if (threadIdx.x == 0) s = 0;
    __syncthreads();
    int c = 0;
    for (int i = threadIdx.x; i < 16384; i += 256) {
        unsigned short u = raw[i];
        if ((u & 0x7F80) == 0x7F80) c++;
    }
    atomicAdd(&s, c);
    __syncthreads();
    if (threadIdx.x == 0) *flag = (s > 0) ? 1 : 0;  // 1 => fp32
}

__global__ void k_init(const void* __restrict__ ue, const void* __restrict__ ie,
                       const int* __restrict__ flag,
                       unsigned short* __restrict__ egoh, float* __restrict__ out) {
    int i = blockIdx.x * blockDim.x + threadIdx.x;
    if (i >= NTOT * EMB) return;
    bool isf32 = (*flag != 0);
    float v;
    if (i < N_USER * EMB) {
        v = isf32 ? ((const float*)ue)[i]
                  : __bfloat162float(((const __hip_bfloat16*)ue)[i]);
    } else {
        int j = i - N_USER * EMB;
        v = isf32 ? ((const float*)ie)[j]
                  : __bfloat162float(((const __hip_bfloat16*)ie)[j]);
    }
    egoh[i] = f2bf(v);
    out[i] = v * (1.0f / 3.0f);   // mean-of-3 accumulator, term 1 (exact fp32)
}

__global__ void k_initL(float* __restrict__ L) {
    int i = blockIdx.x * blockDim.x + threadIdx.x;
    if (i < EDGES * FAC) L[i] = -LOG4;   // log-softmax of all-ones logits
}

// ---- CSR build ----
__global__ void k_deg(const int* __restrict__ h, int* __restrict__ deg) {
    int e = blockIdx.x * blockDim.x + threadIdx.x;
    if (e < EDGES) atomicAdd(&deg[h[e]], 1);
}

__global__ void k_scan1(const int* __restrict__ deg, int* __restrict__ off,
                        int* __restrict__ bsum) {
    __shared__ int buf[SB];
    int tid = threadIdx.x;
    int i = blockIdx.x * SB + tid;
    int v = (i < NTOT) ? deg[i] : 0;
    buf[tid] = v;
    __syncthreads();
    for (int s = 1; s < SB; s <<= 1) {
        int t = (tid >= s) ? buf[tid - s] : 0;
        __syncthreads();
        buf[tid] += t;
        __syncthreads();
    }
    if (i < NTOT) off[i] = buf[tid] - v;
    if (tid == SB - 1) bsum[blockIdx.x] = buf[tid];
}

__global__ void k_scan2(const int* __restrict__ bsum, int* __restrict__ bbase) {
    __shared__ int b[128];
    int tid = threadIdx.x;
    int v = (tid < NBLK) ? bsum[tid] : 0;
    b[tid] = v;
    __syncthreads();
    for (int s = 1; s < 128; s <<= 1) {
        int t = (tid >= s) ? b[tid - s] : 0;
        __syncthreads();
        b[tid] += t;
        __syncthreads();
    }
    if (tid < NBLK) bbase[tid] = b[tid] - v;
}

__global__ void k_scan3(int* __restrict__ off, const int* __restrict__ bbase,
                        int* __restrict__ cur) {
    int i = blockIdx.x * blockDim.x + threadIdx.x;
    if (i < NTOT) {
        int o = off[i] + bbase[i >> 10];
        off[i] = o;
        cur[i] = o;
    }
    if (i == 0) off[NTOT] = EDGES;
}

// single int2 scattered write per edge (halves scattered-line traffic vs 2 arrays)
__global__ void k_scatter(const int* __restrict__ h, const int* __restrict__ t,
                          int* __restrict__ cur, int2* __restrict__ et) {
    int e = blockIdx.x * blockDim.x + threadIdx.x;
    if (e >= EDGES) return;
    int hh = h[e];
    int pos = atomicAdd(&cur[hh], 1);
    et[pos] = make_int2(hh, t[e]);
}

// ---- per-layer: tnhh[n] = bf16(tanh(ego[n] normalized per 16-dim factor)) ----
__global__ void k_tnh(const unsigned short* __restrict__ egoh, unsigned short* __restrict__ tnhh) {
    int gid = blockIdx.x * blockDim.x + threadIdx.x;
    int wid = gid >> 6;
    int lane = threadIdx.x & 63;
    if (wid >= NTOT) return;
    float v = bf2f(egoh[wid * 64 + lane]);
    float ss = v * v;
    ss += __shfl_xor(ss, 1); ss += __shfl_xor(ss, 2);
    ss += __shfl_xor(ss, 4); ss += __shfl_xor(ss, 8);
    float r = 1.0f / fmaxf(sqrtf(ss), 1e-12f);
    tnhh[wid * 64 + lane] = f2bf(tanhf(v * r));
}

// ---- pass 0 dinv: softmax(ones)=0.25 -> dval = 0.25*deg ----
__global__ void k_dinv0(const int* __restrict__ deg, float* __restrict__ dvinv) {
    int i = blockIdx.x * blockDim.x + threadIdx.x;
    if (i >= NTOT * FAC) return;
    float dval = 0.25f * (float)deg[i >> 2];
    dvinv[i] = rsqrtf(fmaxf(dval, 1e-8f));
}

// ---- a: raw dval -> rsqrt in place (becomes next dvinv); z: zero for next accum ----
__global__ void k_rsq(float* __restrict__ a, float* __restrict__ z) {
    int i = blockIdx.x * blockDim.x + threadIdx.x;
    if (i >= NTOT * FAC) return;
    a[i] = rsqrtf(fmaxf(a[i], 1e-8f));
    z[i] = 0.f;
}

// ---- message passing, gather form, bf16 tail rows, unrolled x4 for MLP ----
__global__ void k_mp(const unsigned short* __restrict__ egoh, const float* __restrict__ L,
                     const float* __restrict__ dvinv, const int* __restrict__ off,
                     const int2* __restrict__ et,
                     float* __restrict__ fac, unsigned short* __restrict__ fach,
                     float* __restrict__ rhn,
                     float* __restrict__ out, int writeRhn, int addOut) {
    int gid = blockIdx.x * blockDim.x + threadIdx.x;
    int wid = gid >> 6;
    int lane = threadIdx.x & 63;
    if (wid >= NTOT) return;
    int f = lane >> 4;
    int beg = off[wid], end = off[wid + 1];
    float dvh = dvinv[wid * 4 + f];
    float acc = 0.f;
    int j = beg;
    for (; j + 4 <= end; j += 4) {
        int t0 = et[j].y, t1 = et[j + 1].y, t2 = et[j + 2].y, t3 = et[j + 3].y;
        float l0 = L[(j + 0) * 4 + f], l1 = L[(j + 1) * 4 + f],
              l2 = L[(j + 2) * 4 + f], l3 = L[(j + 3) * 4 + f];
        float d0 = dvinv[t0 * 4 + f], d1 = dvinv[t1 * 4 + f],
              d2 = dvinv[t2 * 4 + f], d3 = dvinv[t3 * 4 + f];
        float g0 = bf2f(egoh[(size_t)t0 * 64 + lane]),
              g1 = bf2f(egoh[(size_t)t1 * 64 + lane]),
              g2 = bf2f(egoh[(size_t)t2 * 64 + lane]),
              g3 = bf2f(egoh[(size_t)t3 * 64 + lane]);
        acc += __expf(l0) * d0 * g0 + __expf(l1) * d1 * g1
             + __expf(l2) * d2 * g2 + __expf(l3) * d3 * g3;
    }
    for (; j < end; ++j) {
        int t = et[j].y;
        acc += __expf(L[j * 4 + f]) * dvinv[t * 4 + f] * bf2f(egoh[(size_t)t * 64 + lane]);
    }
    acc *= dvh;
    fac[wid * 64 + lane] = acc;
    fach[wid * 64 + lane] = f2bf(acc);
    if (addOut) out[wid * 64 + lane] += acc * (1.0f / 3.0f);
    if (writeRhn) {
        float ss = acc * acc;
        ss += __shfl_xor(ss, 1); ss += __shfl_xor(ss, 2);
        ss += __shfl_xor(ss, 4); ss += __shfl_xor(ss, 8);
        if ((lane & 15) == 0) rhn[wid * 4 + f] = 1.0f / fmaxf(sqrtf(ss), 1e-12f);
    }
}

// ---- routing update, edge-parallel, fused with next-pass dval accumulation ----
__global__ void k_upd(const float* __restrict__ fac, const unsigned short* __restrict__ tnhh,
                      const float* __restrict__ rhn, const int2* __restrict__ et,
                      float* __restrict__ L, float* __restrict__ dval) {
    int j = blockIdx.x * blockDim.x + threadIdx.x;
    if (j >= EDGES) return;
    int2 p = et[j];
    int h = p.x, t = p.y;
    const float4* frow = (const float4*)(fac + (size_t)h * 64);
    const uint4*  trow = (const uint4*)(tnhh + (size_t)t * 64);
    float d[4];
#pragma unroll
    for (int f = 0; f < 4; ++f) {
        uint4 u0 = trow[f * 2], u1 = trow[f * 2 + 1];
        float4 a0 = frow[f * 4 + 0], a1 = frow[f * 4 + 1],
               a2 = frow[f * 4 + 2], a3 = frow[f * 4 + 3];
        float x, y0;
        float s = 0.f;
        unpack2(u0.x, x, y0); s += a0.x * x + a0.y * y0;
        unpack2(u0.y, x, y0); s += a0.z * x + a0.w * y0;
        unpack2(u0.z, x, y0); s += a1.x * x + a1.y * y0;
        unpack2(u0.w, x, y0); s += a1.z * x + a1.w * y0;
        unpack2(u1.x, x, y0); s += a2.x * x + a2.y * y0;
        unpack2(u1.y, x, y0); s += a2.z * x + a2.w * y0;
        unpack2(u1.z, x, y0); s += a3.x * x + a3.y * y0;
        unpack2(u1.w, x, y0); s += a3.z * x + a3.w * y0;
        d[f] = s;
    }
    float4 rh = ((const float4*)rhn)[h];
    float4 l0 = ((const float4*)L)[j];
    float y0 = l0.x + rh.x * d[0], y1 = l0.y + rh.y * d[1],
          y2 = l0.z + rh.z * d[2], y3 = l0.w + rh.w * d[3];
    float m = fmaxf(fmaxf(y0, y1), fmaxf(y2, y3));
    float e0 = __expf(y0 - m), e1 = __expf(y1 - m),
          e2 = __expf(y2 - m), e3 = __expf(y3 - m);
    float sum = e0 + e1 + e2 + e3;
    float lse = m + __logf(sum);
    ((float4*)L)[j] = make_float4(y0 - lse, y1 - lse, y2 - lse, y3 - lse);
    float inv = 1.0f / sum;
    float* dv = dval + (size_t)h * 4;
    unsafeAtomicAdd(dv + 0, e0 * inv);
    unsafeAtomicAdd(dv + 1, e1 * inv);
    unsafeAtomicAdd(dv + 2, e2 * inv);
    unsafeAtomicAdd(dv + 3, e3 * inv);
}

extern "C" void kernel_launch(void* const* d_in, const int* in_sizes, int n_in,
                              void* d_out, int out_size, void* d_ws, size_t ws_size,
                              hipStream_t stream) {
    const void* ue = d_in[0];
    const void* ie = d_in[1];
    const int* hl = (const int*)d_in[2];
    const int* tl = (const int*)d_in[3];
    float* out = (float*)d_out;

    float* ws   = (float*)d_ws;
    float* fac  = ws;
    float* L    = ws + 5120000;
    float* dv0  = ws + 9120000;
    float* dv1  = ws + 9440000;
    float* rhn  = ws + 9760000;
    unsigned short* egoh = (unsigned short*)(ws + 10080000);
    unsigned short* fach = (unsigned short*)(ws + 12640000);
    unsigned short* tnhh = (unsigned short*)(ws + 15200000);
    int*   flag = (int*)(ws + 17760000);
    int*   deg  = (int*)(ws + 17760016);
    int*   off  = (int*)(ws + 17840016);
    int*   cur  = (int*)(ws + 17920017);
    int2*  et   = (int2*)(ws + 18000018);
    int*   bsum  = (int*)(ws + 20000018);
    int*   bbase = (int*)(ws + 20000146);

    k_detect<<<1, 256, 0, stream>>>((const unsigned short*)ue, flag);
    k_init<<<20000, 256, 0, stream>>>(ue, ie, flag, egoh, out);
    k_initL<<<15625, 256, 0, stream>>>(L);

    hipMemsetAsync(deg, 0, NTOT * sizeof(int), stream);
    hipMemsetAsync(dv1, 0, NTOT * FAC * sizeof(float), stream);  // first dval accumulator
    k_deg<<<3907, 256, 0, stream>>>(hl, deg);
    k_scan1<<<NBLK, SB, 0, stream>>>(deg, off, bsum);
    k_scan2<<<1, 128, 0, stream>>>(bsum, bbase);
    k_scan3<<<313, 256, 0, stream>>>(off, bbase, cur);
    k_scatter<<<3907, 256, 0, stream>>>(hl, tl, cur, et);

    // layer 0
    k_tnh<<<20000, 256, 0, stream>>>(egoh, tnhh);
    k_dinv0<<<1250, 256, 0, stream>>>(deg, dv0);
    k_mp<<<20000, 256, 0, stream>>>(egoh, L, dv0, off, et, fac, fach, rhn, out, 1, 0); // p0
    k_upd<<<3907, 256, 0, stream>>>(fac, tnhh, rhn, et, L, dv1);
    k_rsq<<<1250, 256, 0, stream>>>(dv1, dv0);
    k_mp<<<20000, 256, 0, stream>>>(egoh, L, dv1, off, et, fac, fach, rhn, out, 1, 1); // p1
    k_upd<<<3907, 256, 0, stream>>>(fac, tnhh, rhn, et, L, dv0);
    k_rsq<<<1250, 256, 0, stream>>>(dv0, dv1);
    // layer 1: factor_emb (fach) becomes the new layer input
    { unsigned short* tmp = egoh; egoh = fach; fach = tmp; }
    k_tnh<<<20000, 256, 0, stream>>>(egoh, tnhh);
    k_mp<<<20000, 256, 0, stream>>>(egoh, L, dv0, off, et, fac, fach, rhn, out, 1, 0); // p2
    k_upd<<<3907, 256, 0, stream>>>(fac, tnhh, rhn, et, L, dv1);
    k_rsq<<<1250, 256, 0, stream>>>(dv1, dv0);
    k_mp<<<20000, 256, 0, stream>>>(egoh, L, dv1, off, et, fac, fach, rhn, out, 0, 1); // p3
}

// Round 8
// 596.965 us; speedup vs baseline: 1.9996x; 1.9996x over previous
//
#include <hip/hip_runtime.h>
#include <hip/hip_bf16.h>

#define N_USER 50000
#define N_ITEM 30000
#define NTOT   80000
#define EMB    64
#define FAC    4
#define EDGES  1000000
#define LOG4   1.3862943611198906f
#define SB     1024
#define NBLK   79   // ceil(80000/1024)

// ws layout (float idx), ~80 MB:
//   fac   +0          5,120,000  (fp32 current-pass factor_emb, for k_upd dot + rhn)
//   L     +5,120,000  4,000,000  (log-softmax of A, CSR position order)
//   dv    +9,120,000    320,000  (dvinv)
//   rhn   +9,760,000    320,000
//   egoh  +10,080,000 2,560,000  (bf16 layer-input embeddings)
//   fach  +12,640,000 2,560,000  (bf16 layer-output embeddings)
//   tnhh  +15,200,000 2,560,000  (bf16 tanh-normalized tails)
//   flag  +17,760,000  16
//   deg   +17,760,016  80,000 | off +17,840,016 80,001 | cur +17,920,017 80,000
//   et    +18,000,018  2,000,000 (int2 per CSR pos: {h,t})
//   bsum  +20,000,018  128 | bbase +20,000,146 128

__device__ inline float bf2f(unsigned short u) {
    return __uint_as_float(((unsigned int)u) << 16);
}
__device__ inline unsigned short f2bf(float f) {
    unsigned int x = __float_as_uint(f);
    x += 0x7FFFu + ((x >> 16) & 1u);       // round-to-nearest-even
    return (unsigned short)(x >> 16);
}
__device__ inline void unpack2(unsigned int u, float& a, float& b) {
    a = __uint_as_float(u << 16);
    b = __uint_as_float(u & 0xFFFF0000u);
}

// ---- input dtype detector (fp32 read-as-bf16 shows inf/NaN bit patterns) ----
__global__ void k_detect(const unsigned short* __restrict__ raw, int* __restrict__ flag) {
    __shared__ int s;
    if (threadIdx.x == 0) s = 0;
    __syncthreads();
    int c = 0;
    for (int i = threadIdx.x; i < 16384; i += 256) {
        unsigned short u = raw[i];
        if ((u & 0x7F80) == 0x7F80) c++;
    }
    atomicAdd(&s, c);
    __syncthreads();
    if (threadIdx.x == 0) *flag = (s > 0) ? 1 : 0;  // 1 => fp32
}

__global__ void k_init(const void* __restrict__ ue, const void* __restrict__ ie,
                       const int* __restrict__ flag,
                       unsigned short* __restrict__ egoh, float* __restrict__ out) {
    int i = blockIdx.x * blockDim.x + threadIdx.x;
    if (i >= NTOT * EMB) return;
    bool isf32 = (*flag != 0);
    float v;
    if (i < N_USER * EMB) {
        v = isf32 ? ((const float*)ue)[i]
                  : __bfloat162float(((const __hip_bfloat16*)ue)[i]);
    } else {
        int j = i - N_USER * EMB;
        v = isf32 ? ((const float*)ie)[j]
                  : __bfloat162float(((const __hip_bfloat16*)ie)[j]);
    }
    egoh[i] = f2bf(v);
    out[i] = v * (1.0f / 3.0f);   // mean-of-3 accumulator, term 1 (exact fp32)
}

__global__ void k_initL(float* __restrict__ L) {
    int i = blockIdx.x * blockDim.x + threadIdx.x;
    if (i < EDGES * FAC) L[i] = -LOG4;   // log-softmax of all-ones logits
}

// ---- CSR build ----
__global__ void k_deg(const int* __restrict__ h, int* __restrict__ deg) {
    int e = blockIdx.x * blockDim.x + threadIdx.x;
    if (e < EDGES) atomicAdd(&deg[h[e]], 1);
}

__global__ void k_scan1(const int* __restrict__ deg, int* __restrict__ off,
                        int* __restrict__ bsum) {
    __shared__ int buf[SB];
    int tid = threadIdx.x;
    int i = blockIdx.x * SB + tid;
    int v = (i < NTOT) ? deg[i] : 0;
    buf[tid] = v;
    __syncthreads();
    for (int s = 1; s < SB; s <<= 1) {
        int t = (tid >= s) ? buf[tid - s] : 0;
        __syncthreads();
        buf[tid] += t;
        __syncthreads();
    }
    if (i < NTOT) off[i] = buf[tid] - v;
    if (tid == SB - 1) bsum[blockIdx.x] = buf[tid];
}

__global__ void k_scan2(const int* __restrict__ bsum, int* __restrict__ bbase) {
    __shared__ int b[128];
    int tid = threadIdx.x;
    int v = (tid < NBLK) ? bsum[tid] : 0;
    b[tid] = v;
    __syncthreads();
    for (int s = 1; s < 128; s <<= 1) {
        int t = (tid >= s) ? b[tid - s] : 0;
        __syncthreads();
        b[tid] += t;
        __syncthreads();
    }
    if (tid < NBLK) bbase[tid] = b[tid] - v;
}

__global__ void k_scan3(int* __restrict__ off, const int* __restrict__ bbase,
                        int* __restrict__ cur) {
    int i = blockIdx.x * blockDim.x + threadIdx.x;
    if (i < NTOT) {
        int o = off[i] + bbase[i >> 10];
        off[i] = o;
        cur[i] = o;
    }
    if (i == 0) off[NTOT] = EDGES;
}

__global__ void k_scatter(const int* __restrict__ h, const int* __restrict__ t,
                          int* __restrict__ cur, int2* __restrict__ et) {
    int e = blockIdx.x * blockDim.x + threadIdx.x;
    if (e >= EDGES) return;
    int hh = h[e];
    int pos = atomicAdd(&cur[hh], 1);
    et[pos] = make_int2(hh, t[e]);
}

// ---- per-layer: tnhh[n] = bf16(tanh(ego[n] normalized per 16-dim factor)) ----
__global__ void k_tnh(const unsigned short* __restrict__ egoh, unsigned short* __restrict__ tnhh) {
    int gid = blockIdx.x * blockDim.x + threadIdx.x;
    int wid = gid >> 6;
    int lane = threadIdx.x & 63;
    if (wid >= NTOT) return;
    float v = bf2f(egoh[wid * 64 + lane]);
    float ss = v * v;
    ss += __shfl_xor(ss, 1); ss += __shfl_xor(ss, 2);
    ss += __shfl_xor(ss, 4); ss += __shfl_xor(ss, 8);
    float r = 1.0f / fmaxf(sqrtf(ss), 1e-12f);
    tnhh[wid * 64 + lane] = f2bf(tanhf(v * r));
}

// ---- pass 0 dinv: softmax(ones)=0.25 -> dval = 0.25*deg ----
__global__ void k_dinv0(const int* __restrict__ deg, float* __restrict__ dvinv) {
    int i = blockIdx.x * blockDim.x + threadIdx.x;
    if (i >= NTOT * FAC) return;
    float dval = 0.25f * (float)deg[i >> 2];
    dvinv[i] = rsqrtf(fmaxf(dval, 1e-8f));
}

// ---- dvinv[n,f] = rsqrt(sum_j exp(L[j,f])); quad of lanes per node; coalesced L ----
__global__ void k_dv(const float* __restrict__ L, const int* __restrict__ off,
                     float* __restrict__ dvinv) {
    int tid = blockIdx.x * blockDim.x + threadIdx.x;
    if (tid >= NTOT * FAC) return;
    int n = tid >> 2, f = tid & 3;
    int beg = off[n], end = off[n + 1];
    float s = 0.f;
    for (int j = beg; j < end; ++j) s += __expf(L[j * 4 + f]);
    dvinv[tid] = rsqrtf(fmaxf(s, 1e-8f));
}

// ---- message passing, gather form, bf16 tail rows, unrolled x4 for MLP ----
__global__ void k_mp(const unsigned short* __restrict__ egoh, const float* __restrict__ L,
                     const float* __restrict__ dvinv, const int* __restrict__ off,
                     const int2* __restrict__ et,
                     float* __restrict__ fac, unsigned short* __restrict__ fach,
                     float* __restrict__ rhn,
                     float* __restrict__ out, int writeRhn, int addOut) {
    int gid = blockIdx.x * blockDim.x + threadIdx.x;
    int wid = gid >> 6;
    int lane = threadIdx.x & 63;
    if (wid >= NTOT) return;
    int f = lane >> 4;
    int beg = off[wid], end = off[wid + 1];
    float dvh = dvinv[wid * 4 + f];
    float acc = 0.f;
    int j = beg;
    for (; j + 4 <= end; j += 4) {
        int t0 = et[j].y, t1 = et[j + 1].y, t2 = et[j + 2].y, t3 = et[j + 3].y;
        float l0 = L[(j + 0) * 4 + f], l1 = L[(j + 1) * 4 + f],
              l2 = L[(j + 2) * 4 + f], l3 = L[(j + 3) * 4 + f];
        float d0 = dvinv[t0 * 4 + f], d1 = dvinv[t1 * 4 + f],
              d2 = dvinv[t2 * 4 + f], d3 = dvinv[t3 * 4 + f];
        float g0 = bf2f(egoh[(size_t)t0 * 64 + lane]),
              g1 = bf2f(egoh[(size_t)t1 * 64 + lane]),
              g2 = bf2f(egoh[(size_t)t2 * 64 + lane]),
              g3 = bf2f(egoh[(size_t)t3 * 64 + lane]);
        acc += __expf(l0) * d0 * g0 + __expf(l1) * d1 * g1
             + __expf(l2) * d2 * g2 + __expf(l3) * d3 * g3;
    }
    for (; j < end; ++j) {
        int t = et[j].y;
        acc += __expf(L[j * 4 + f]) * dvinv[t * 4 + f] * bf2f(egoh[(size_t)t * 64 + lane]);
    }
    acc *= dvh;
    fac[wid * 64 + lane] = acc;
    fach[wid * 64 + lane] = f2bf(acc);
    if (addOut) out[wid * 64 + lane] += acc * (1.0f / 3.0f);
    if (writeRhn) {
        float ss = acc * acc;
        ss += __shfl_xor(ss, 1); ss += __shfl_xor(ss, 2);
        ss += __shfl_xor(ss, 4); ss += __shfl_xor(ss, 8);
        if ((lane & 15) == 0) rhn[wid * 4 + f] = 1.0f / fmaxf(sqrtf(ss), 1e-12f);
    }
}

// ---- routing update, edge-parallel: writes L only (NO scattered atomics) ----
__global__ void k_upd(const float* __restrict__ fac, const unsigned short* __restrict__ tnhh,
                      const float* __restrict__ rhn, const int2* __restrict__ et,
                      float* __restrict__ L) {
    int j = blockIdx.x * blockDim.x + threadIdx.x;
    if (j >= EDGES) return;
    int2 p = et[j];
    int h = p.x, t = p.y;
    const float4* frow = (const float4*)(fac + (size_t)h * 64);
    const uint4*  trow = (const uint4*)(tnhh + (size_t)t * 64);
    float d[4];
#pragma unroll
    for (int f = 0; f < 4; ++f) {
        uint4 u0 = trow[f * 2], u1 = trow[f * 2 + 1];
        float4 a0 = frow[f * 4 + 0], a1 = frow[f * 4 + 1],
               a2 = frow[f * 4 + 2], a3 = frow[f * 4 + 3];
        float x, y0;
        float s = 0.f;
        unpack2(u0.x, x, y0); s += a0.x * x + a0.y * y0;
        unpack2(u0.y, x, y0); s += a0.z * x + a0.w * y0;
        unpack2(u0.z, x, y0); s += a1.x * x + a1.y * y0;
        unpack2(u0.w, x, y0); s += a1.z * x + a1.w * y0;
        unpack2(u1.x, x, y0); s += a2.x * x + a2.y * y0;
        unpack2(u1.y, x, y0); s += a2.z * x + a2.w * y0;
        unpack2(u1.z, x, y0); s += a3.x * x + a3.y * y0;
        unpack2(u1.w, x, y0); s += a3.z * x + a3.w * y0;
        d[f] = s;
    }
    float4 rh = ((const float4*)rhn)[h];
    float4 l0 = ((const float4*)L)[j];
    float y0 = l0.x + rh.x * d[0], y1 = l0.y + rh.y * d[1],
          y2 = l0.z + rh.z * d[2], y3 = l0.w + rh.w * d[3];
    float m = fmaxf(fmaxf(y0, y1), fmaxf(y2, y3));
    float e0 = __expf(y0 - m), e1 = __expf(y1 - m),
          e2 = __expf(y2 - m), e3 = __expf(y3 - m);
    float lse = m + __logf(e0 + e1 + e2 + e3);
    ((float4*)L)[j] = make_float4(y0 - lse, y1 - lse, y2 - lse, y3 - lse);
}

extern "C" void kernel_launch(void* const* d_in, const int* in_sizes, int n_in,
                              void* d_out, int out_size, void* d_ws, size_t ws_size,
                              hipStream_t stream) {
    const void* ue = d_in[0];
    const void* ie = d_in[1];
    const int* hl = (const int*)d_in[2];
    const int* tl = (const int*)d_in[3];
    float* out = (float*)d_out;

    float* ws   = (float*)d_ws;
    float* fac  = ws;
    float* L    = ws + 5120000;
    float* dv   = ws + 9120000;
    float* rhn  = ws + 9760000;
    unsigned short* egoh = (unsigned short*)(ws + 10080000);
    unsigned short* fach = (unsigned short*)(ws + 12640000);
    unsigned short* tnhh = (unsigned short*)(ws + 15200000);
    int*   flag = (int*)(ws + 17760000);
    int*   deg  = (int*)(ws + 17760016);
    int*   off  = (int*)(ws + 17840016);
    int*   cur  = (int*)(ws + 17920017);
    int2*  et   = (int2*)(ws + 18000018);
    int*   bsum  = (int*)(ws + 20000018);
    int*   bbase = (int*)(ws + 20000146);

    k_detect<<<1, 256, 0, stream>>>((const unsigned short*)ue, flag);
    k_init<<<20000, 256, 0, stream>>>(ue, ie, flag, egoh, out);
    k_initL<<<15625, 256, 0, stream>>>(L);

    hipMemsetAsync(deg, 0, NTOT * sizeof(int), stream);
    k_deg<<<3907, 256, 0, stream>>>(hl, deg);
    k_scan1<<<NBLK, SB, 0, stream>>>(deg, off, bsum);
    k_scan2<<<1, 128, 0, stream>>>(bsum, bbase);
    k_scan3<<<313, 256, 0, stream>>>(off, bbase, cur);
    k_scatter<<<3907, 256, 0, stream>>>(hl, tl, cur, et);

    // layer 0
    k_tnh<<<20000, 256, 0, stream>>>(egoh, tnhh);
    k_dinv0<<<1250, 256, 0, stream>>>(deg, dv);
    k_mp<<<20000, 256, 0, stream>>>(egoh, L, dv, off, et, fac, fach, rhn, out, 1, 0); // p0
    k_upd<<<3907, 256, 0, stream>>>(fac, tnhh, rhn, et, L);
    k_dv<<<1250, 256, 0, stream>>>(L, off, dv);
    k_mp<<<20000, 256, 0, stream>>>(egoh, L, dv, off, et, fac, fach, rhn, out, 1, 1); // p1
    k_upd<<<3907, 256, 0, stream>>>(fac, tnhh, rhn, et, L);
    k_dv<<<1250, 256, 0, stream>>>(L, off, dv);
    // layer 1: factor_emb (fach) becomes the new layer input
    { unsigned short* tmp = egoh; egoh = fach; fach = tmp; }
    k_tnh<<<20000, 256, 0, stream>>>(egoh, tnhh);
    k_mp<<<20000, 256, 0, stream>>>(egoh, L, dv, off, et, fac, fach, rhn, out, 1, 0); // p2
    k_upd<<<3907, 256, 0, stream>>>(fac, tnhh, rhn, et, L);
    k_dv<<<1250, 256, 0, stream>>>(L, off, dv);
    k_mp<<<20000, 256, 0, stream>>>(egoh, L, dv, off, et, fac, fach, rhn, out, 0, 1); // p3
}

// Round 9
// 558.475 us; speedup vs baseline: 2.1374x; 1.0689x over previous
//
#include <hip/hip_runtime.h>
#include <hip/hip_bf16.h>

#define N_USER 50000
#define N_ITEM 30000
#define NTOT   80000
#define EMB    64
#define FAC    4
#define EDGES  1000000
#define LOG4   1.3862943611198906f
#define SB     1024
#define NBLK   79   // ceil(80000/1024)

// ws layout (float idx), ~58 MB:
//   L     +0          4,000,000  (log-softmax of A, CSR position order)
//   dv    +4,000,000    320,000  (dvinv)
//   rhn   +4,320,000    320,000
//   egoh  +4,640,000  2,560,000  (bf16 layer-input embeddings, 5.12M ushort)
//   fach  +7,200,000  2,560,000  (bf16 layer-output embeddings)
//   tnhh  +9,760,000  2,560,000  (bf16 tanh-normalized tails)
//   flag  +12,320,000  16
//   deg   +12,320,016  80,000 | off +12,400,016 80,001 | cur +12,480,017 80,000
//   et    +12,560,018  2,000,000 (int2 per CSR pos: {h,t}; even -> 8B aligned)
//   bsum  +14,560,018  128 | bbase +14,560,146 128

__device__ inline float bf2f(unsigned short u) {
    return __uint_as_float(((unsigned int)u) << 16);
}
__device__ inline unsigned short f2bf(float f) {
    unsigned int x = __float_as_uint(f);
    x += 0x7FFFu + ((x >> 16) & 1u);       // round-to-nearest-even
    return (unsigned short)(x >> 16);
}
__device__ inline float dot2(unsigned int a, unsigned int b) {
    float a0 = __uint_as_float(a << 16), a1 = __uint_as_float(a & 0xFFFF0000u);
    float b0 = __uint_as_float(b << 16), b1 = __uint_as_float(b & 0xFFFF0000u);
    return a0 * b0 + a1 * b1;
}

// ---- input dtype detector (fp32 read-as-bf16 shows inf/NaN bit patterns) ----
__global__ void k_detect(const unsigned short* __restrict__ raw, int* __restrict__ flag) {
    __shared__ int s;
    if (threadIdx.x == 0) s = 0;
    __syncthreads();
    int c = 0;
    for (int i = threadIdx.x; i < 16384; i += 256) {
        unsigned short u = raw[i];
        if ((u & 0x7F80) == 0x7F80) c++;
    }
    atomicAdd(&s, c);
    __syncthreads();
    if (threadIdx.x == 0) *flag = (s > 0) ? 1 : 0;  // 1 => fp32
}

__global__ void k_init(const void* __restrict__ ue, const void* __restrict__ ie,
                       const int* __restrict__ flag,
                       unsigned short* __restrict__ egoh, float* __restrict__ out) {
    int i = blockIdx.x * blockDim.x + threadIdx.x;
    if (i >= NTOT * EMB) return;
    bool isf32 = (*flag != 0);
    float v;
    if (i < N_USER * EMB) {
        v = isf32 ? ((const float*)ue)[i]
                  : __bfloat162float(((const __hip_bfloat16*)ue)[i]);
    } else {
        int j = i - N_USER * EMB;
        v = isf32 ? ((const float*)ie)[j]
                  : __bfloat162float(((const __hip_bfloat16*)ie)[j]);
    }
    egoh[i] = f2bf(v);
    out[i] = v * (1.0f / 3.0f);   // mean-of-3 accumulator, term 1 (exact fp32)
}

// ---- CSR build ----
__global__ void k_deg(const int* __restrict__ h, int* __restrict__ deg) {
    int e = blockIdx.x * blockDim.x + threadIdx.x;
    if (e < EDGES) atomicAdd(&deg[h[e]], 1);
}

__global__ void k_scan1(const int* __restrict__ deg, int* __restrict__ off,
                        int* __restrict__ bsum) {
    __shared__ int buf[SB];
    int tid = threadIdx.x;
    int i = blockIdx.x * SB + tid;
    int v = (i < NTOT) ? deg[i] : 0;
    buf[tid] = v;
    __syncthreads();
    for (int s = 1; s < SB; s <<= 1) {
        int t = (tid >= s) ? buf[tid - s] : 0;
        __syncthreads();
        buf[tid] += t;
        __syncthreads();
    }
    if (i < NTOT) off[i] = buf[tid] - v;
    if (tid == SB - 1) bsum[blockIdx.x] = buf[tid];
}

__global__ void k_scan2(const int* __restrict__ bsum, int* __restrict__ bbase) {
    __shared__ int b[128];
    int tid = threadIdx.x;
    int v = (tid < NBLK) ? bsum[tid] : 0;
    b[tid] = v;
    __syncthreads();
    for (int s = 1; s < 128; s <<= 1) {
        int t = (tid >= s) ? b[tid - s] : 0;
        __syncthreads();
        b[tid] += t;
        __syncthreads();
    }
    if (tid < NBLK) bbase[tid] = b[tid] - v;
}

__global__ void k_scan3(int* __restrict__ off, const int* __restrict__ bbase,
                        int* __restrict__ cur) {
    int i = blockIdx.x * blockDim.x + threadIdx.x;
    if (i < NTOT) {
        int o = off[i] + bbase[i >> 10];
        off[i] = o;
        cur[i] = o;
    }
    if (i == 0) off[NTOT] = EDGES;
}

__global__ void k_scatter(const int* __restrict__ h, const int* __restrict__ t,
                          int* __restrict__ cur, int2* __restrict__ et) {
    int e = blockIdx.x * blockDim.x + threadIdx.x;
    if (e >= EDGES) return;
    int hh = h[e];
    int pos = atomicAdd(&cur[hh], 1);
    et[pos] = make_int2(hh, t[e]);
}

// ---- per-layer: tnhh[n] = bf16(tanh(ego[n] normalized per 16-dim factor)) ----
__global__ void k_tnh(const unsigned short* __restrict__ egoh, unsigned short* __restrict__ tnhh) {
    int gid = blockIdx.x * blockDim.x + threadIdx.x;
    int wid = gid >> 6;
    int lane = threadIdx.x & 63;
    if (wid >= NTOT) return;
    float v = bf2f(egoh[wid * 64 + lane]);
    float ss = v * v;
    ss += __shfl_xor(ss, 1); ss += __shfl_xor(ss, 2);
    ss += __shfl_xor(ss, 4); ss += __shfl_xor(ss, 8);
    float r = 1.0f / fmaxf(sqrtf(ss), 1e-12f);
    tnhh[wid * 64 + lane] = f2bf(tanhf(v * r));
}

// ---- pass 0 dinv: softmax(ones)=0.25 -> dval = 0.25*deg ----
__global__ void k_dinv0(const int* __restrict__ deg, float* __restrict__ dvinv) {
    int i = blockIdx.x * blockDim.x + threadIdx.x;
    if (i >= NTOT * FAC) return;
    float dval = 0.25f * (float)deg[i >> 2];
    dvinv[i] = rsqrtf(fmaxf(dval, 1e-8f));
}

// ---- dvinv[n,f] = rsqrt(sum_j exp(L[j,f])); quad of lanes per node; coalesced L ----
__global__ void k_dv(const float* __restrict__ L, const int* __restrict__ off,
                     float* __restrict__ dvinv) {
    int tid = blockIdx.x * blockDim.x + threadIdx.x;
    if (tid >= NTOT * FAC) return;
    int n = tid >> 2, f = tid & 3;
    int beg = off[n], end = off[n + 1];
    float s = 0.f;
    for (int j = beg; j < end; ++j) s += __expf(L[j * 4 + f]);
    dvinv[tid] = rsqrtf(fmaxf(s, 1e-8f));
}

// ---- message passing, gather form, bf16 tail rows, unrolled x4 for MLP ----
// useL=0: weight 0.25 (pass 0, L is implicitly -log4 for every edge)
__global__ void k_mp(const unsigned short* __restrict__ egoh, const float* __restrict__ L,
                     const float* __restrict__ dvinv, const int* __restrict__ off,
                     const int2* __restrict__ et,
                     unsigned short* __restrict__ fach, float* __restrict__ rhn,
                     float* __restrict__ out, int useL, int writeRhn, int addOut) {
    int gid = blockIdx.x * blockDim.x + threadIdx.x;
    int wid = gid >> 6;
    int lane = threadIdx.x & 63;
    if (wid >= NTOT) return;
    int f = lane >> 4;
    int beg = off[wid], end = off[wid + 1];
    float dvh = dvinv[wid * 4 + f];
    float acc = 0.f;
    int j = beg;
    for (; j + 4 <= end; j += 4) {
        int t0 = et[j].y, t1 = et[j + 1].y, t2 = et[j + 2].y, t3 = et[j + 3].y;
        float w0, w1, w2, w3;
        if (useL) {
            w0 = __expf(L[(j + 0) * 4 + f]); w1 = __expf(L[(j + 1) * 4 + f]);
            w2 = __expf(L[(j + 2) * 4 + f]); w3 = __expf(L[(j + 3) * 4 + f]);
        } else {
            w0 = w1 = w2 = w3 = 0.25f;
        }
        float d0 = dvinv[t0 * 4 + f], d1 = dvinv[t1 * 4 + f],
              d2 = dvinv[t2 * 4 + f], d3 = dvinv[t3 * 4 + f];
        float g0 = bf2f(egoh[(size_t)t0 * 64 + lane]),
              g1 = bf2f(egoh[(size_t)t1 * 64 + lane]),
              g2 = bf2f(egoh[(size_t)t2 * 64 + lane]),
              g3 = bf2f(egoh[(size_t)t3 * 64 + lane]);
        acc += w0 * d0 * g0 + w1 * d1 * g1 + w2 * d2 * g2 + w3 * d3 * g3;
    }
    for (; j < end; ++j) {
        int t = et[j].y;
        float w = useL ? __expf(L[j * 4 + f]) : 0.25f;
        acc += w * dvinv[t * 4 + f] * bf2f(egoh[(size_t)t * 64 + lane]);
    }
    acc *= dvh;
    fach[wid * 64 + lane] = f2bf(acc);
    if (addOut) out[wid * 64 + lane] += acc * (1.0f / 3.0f);
    if (writeRhn) {
        float ss = acc * acc;
        ss += __shfl_xor(ss, 1); ss += __shfl_xor(ss, 2);
        ss += __shfl_xor(ss, 4); ss += __shfl_xor(ss, 8);
        if ((lane & 15) == 0) rhn[wid * 4 + f] = 1.0f / fmaxf(sqrtf(ss), 1e-12f);
    }
}

// ---- routing update, edge-parallel, all-bf16 gathers; first=1 -> L_old = -log4 ----
__global__ void k_upd(const unsigned short* __restrict__ fach,
                      const unsigned short* __restrict__ tnhh,
                      const float* __restrict__ rhn, const int2* __restrict__ et,
                      float* __restrict__ L, int first) {
    int j = blockIdx.x * blockDim.x + threadIdx.x;
    if (j >= EDGES) return;
    int2 p = et[j];
    int h = p.x, t = p.y;
    const uint4* frow = (const uint4*)(fach + (size_t)h * 64);
    const uint4* trow = (const uint4*)(tnhh + (size_t)t * 64);
    float d[4];
#pragma unroll
    for (int f = 0; f < 4; ++f) {
        uint4 a0 = frow[f * 2], a1 = frow[f * 2 + 1];
        uint4 b0 = trow[f * 2], b1 = trow[f * 2 + 1];
        float s = dot2(a0.x, b0.x) + dot2(a0.y, b0.y)
                + dot2(a0.z, b0.z) + dot2(a0.w, b0.w)
                + dot2(a1.x, b1.x) + dot2(a1.y, b1.y)
                + dot2(a1.z, b1.z) + dot2(a1.w, b1.w);
        d[f] = s;
    }
    float4 rh = ((const float4*)rhn)[h];
    float lx, ly, lz, lw;
    if (first) { lx = ly = lz = lw = -LOG4; }
    else { float4 l0 = ((const float4*)L)[j]; lx = l0.x; ly = l0.y; lz = l0.z; lw = l0.w; }
    float y0 = lx + rh.x * d[0], y1 = ly + rh.y * d[1],
          y2 = lz + rh.z * d[2], y3 = lw + rh.w * d[3];
    float m = fmaxf(fmaxf(y0, y1), fmaxf(y2, y3));
    float e0 = __expf(y0 - m), e1 = __expf(y1 - m),
          e2 = __expf(y2 - m), e3 = __expf(y3 - m);
    float lse = m + __logf(e0 + e1 + e2 + e3);
    ((float4*)L)[j] = make_float4(y0 - lse, y1 - lse, y2 - lse, y3 - lse);
}

extern "C" void kernel_launch(void* const* d_in, const int* in_sizes, int n_in,
                              void* d_out, int out_size, void* d_ws, size_t ws_size,
                              hipStream_t stream) {
    const void* ue = d_in[0];
    const void* ie = d_in[1];
    const int* hl = (const int*)d_in[2];
    const int* tl = (const int*)d_in[3];
    float* out = (float*)d_out;

    float* ws   = (float*)d_ws;
    float* L    = ws;
    float* dv   = ws + 4000000;
    float* rhn  = ws + 4320000;
    unsigned short* egoh = (unsigned short*)(ws + 4640000);
    unsigned short* fach = (unsigned short*)(ws + 7200000);
    unsigned short* tnhh = (unsigned short*)(ws + 9760000);
    int*   flag = (int*)(ws + 12320000);
    int*   deg  = (int*)(ws + 12320016);
    int*   off  = (int*)(ws + 12400016);
    int*   cur  = (int*)(ws + 12480017);
    int2*  et   = (int2*)(ws + 12560018);
    int*   bsum  = (int*)(ws + 14560018);
    int*   bbase = (int*)(ws + 14560146);

    k_detect<<<1, 256, 0, stream>>>((const unsigned short*)ue, flag);
    k_init<<<20000, 256, 0, stream>>>(ue, ie, flag, egoh, out);

    hipMemsetAsync(deg, 0, NTOT * sizeof(int), stream);
    k_deg<<<3907, 256, 0, stream>>>(hl, deg);
    k_scan1<<<NBLK, SB, 0, stream>>>(deg, off, bsum);
    k_scan2<<<1, 128, 0, stream>>>(bsum, bbase);
    k_scan3<<<313, 256, 0, stream>>>(off, bbase, cur);
    k_scatter<<<3907, 256, 0, stream>>>(hl, tl, cur, et);

    // layer 0
    k_tnh<<<20000, 256, 0, stream>>>(egoh, tnhh);
    k_dinv0<<<1250, 256, 0, stream>>>(deg, dv);
    k_mp<<<20000, 256, 0, stream>>>(egoh, L, dv, off, et, fach, rhn, out, 0, 1, 0); // p0
    k_upd<<<3907, 256, 0, stream>>>(fach, tnhh, rhn, et, L, 1);
    k_dv<<<1250, 256, 0, stream>>>(L, off, dv);
    k_mp<<<20000, 256, 0, stream>>>(egoh, L, dv, off, et, fach, rhn, out, 1, 1, 1); // p1
    k_upd<<<3907, 256, 0, stream>>>(fach, tnhh, rhn, et, L, 0);
    k_dv<<<1250, 256, 0, stream>>>(L, off, dv);
    // layer 1: factor_emb (fach) becomes the new layer input
    { unsigned short* tmp = egoh; egoh = fach; fach = tmp; }
    k_tnh<<<20000, 256, 0, stream>>>(egoh, tnhh);
    k_mp<<<20000, 256, 0, stream>>>(egoh, L, dv, off, et, fach, rhn, out, 1, 1, 0); // p2
    k_upd<<<3907, 256, 0, stream>>>(fach, tnhh, rhn, et, L, 0);
    k_dv<<<1250, 256, 0, stream>>>(L, off, dv);
    k_mp<<<20000, 256, 0, stream>>>(egoh, L, dv, off, et, fach, rhn, out, 1, 0, 1); // p3
}

// Round 10
// 539.617 us; speedup vs baseline: 2.2121x; 1.0349x over previous
//
#include <hip/hip_runtime.h>
#include <hip/hip_bf16.h>

#define N_USER 50000
#define N_ITEM 30000
#define NTOT   80000
#define EMB    64
#define FAC    4
#define EDGES  1000000
#define LOG4   1.3862943611198906f
#define SB     1024
#define NBLK   79   // ceil(80000/1024)

// ws layout (float idx), ~70 MB:
//   L     +0          4,000,000  (log-softmax of A, CSR position order)
//   dv0   +4,000,000    320,000  (raw dval ping; k_mp applies rsqrt on the fly)
//   dv1   +4,320,000    320,000  (raw dval pong)
//   rhn   +4,640,000    320,000
//   egoA  +4,960,000  2,560,000  (bf16)
//   egoB  +7,520,000  2,560,000  (bf16)
//   tnh0  +10,080,000 2,560,000  (bf16 layer-0 tanh-normalized)
//   tnh1  +12,640,000 2,560,000  (bf16 layer-1 tanh-normalized)
//   flag  +15,200,000 16
//   deg   +15,200,016 80,000 | off +15,280,016 80,001 | cur +15,360,017 80,000
//   et    +15,440,018 2,000,000 (int2 {h,t} per CSR pos; even idx -> 8B aligned)
//   bsum  +17,440,018 128 | bbase +17,440,146 128

__device__ inline float bf2f(unsigned short u) {
    return __uint_as_float(((unsigned int)u) << 16);
}
__device__ inline unsigned short f2bf(float f) {
    unsigned int x = __float_as_uint(f);
    x += 0x7FFFu + ((x >> 16) & 1u);       // round-to-nearest-even
    return (unsigned short)(x >> 16);
}
__device__ inline float dot2(unsigned int a, unsigned int b) {
    float a0 = __uint_as_float(a << 16), a1 = __uint_as_float(a & 0xFFFF0000u);
    float b0 = __uint_as_float(b << 16), b1 = __uint_as_float(b & 0xFFFF0000u);
    return a0 * b0 + a1 * b1;
}

// ---- input dtype detector (fp32 read-as-bf16 shows inf/NaN bit patterns) ----
__global__ void k_detect(const unsigned short* __restrict__ raw, int* __restrict__ flag) {
    __shared__ int s;
    if (threadIdx.x == 0) s = 0;
    __syncthreads();
    int c = 0;
    for (int i = threadIdx.x; i < 16384; i += 256) {
        unsigned short u = raw[i];
        if ((u & 0x7F80) == 0x7F80) c++;
    }
    atomicAdd(&s, c);
    __syncthreads();
    if (threadIdx.x == 0) *flag = (s > 0) ? 1 : 0;  // 1 => fp32
}

// ---- init: ego(bf16), out accumulator, and layer-0 tnh (fused, wave-per-node) ----
__global__ void k_init(const void* __restrict__ ue, const void* __restrict__ ie,
                       const int* __restrict__ flag,
                       unsigned short* __restrict__ egoh, float* __restrict__ out,
                       unsigned short* __restrict__ tnh0) {
    int gid = blockIdx.x * blockDim.x + threadIdx.x;
    int wid = gid >> 6;
    int lane = threadIdx.x & 63;
    if (wid >= NTOT) return;
    int i = wid * 64 + lane;
    bool isf32 = (*flag != 0);
    float v;
    if (i < N_USER * EMB) {
        v = isf32 ? ((const float*)ue)[i]
                  : __bfloat162float(((const __hip_bfloat16*)ue)[i]);
    } else {
        int j = i - N_USER * EMB;
        v = isf32 ? ((const float*)ie)[j]
                  : __bfloat162float(((const __hip_bfloat16*)ie)[j]);
    }
    egoh[i] = f2bf(v);
    out[i] = v * (1.0f / 3.0f);   // mean-of-3 accumulator, term 1 (exact fp32)
    float ss = v * v;
    ss += __shfl_xor(ss, 1); ss += __shfl_xor(ss, 2);
    ss += __shfl_xor(ss, 4); ss += __shfl_xor(ss, 8);
    float rr = 1.0f / fmaxf(sqrtf(ss), 1e-12f);
    tnh0[i] = f2bf(tanhf(v * rr));
}

// ---- CSR build ----
__global__ void k_deg(const int* __restrict__ h, int* __restrict__ deg) {
    int e = blockIdx.x * blockDim.x + threadIdx.x;
    if (e < EDGES) atomicAdd(&deg[h[e]], 1);
}

__global__ void k_scan1(const int* __restrict__ deg, int* __restrict__ off,
                        int* __restrict__ bsum) {
    __shared__ int buf[SB];
    int tid = threadIdx.x;
    int i = blockIdx.x * SB + tid;
    int v = (i < NTOT) ? deg[i] : 0;
    buf[tid] = v;
    __syncthreads();
    for (int s = 1; s < SB; s <<= 1) {
        int t = (tid >= s) ? buf[tid - s] : 0;
        __syncthreads();
        buf[tid] += t;
        __syncthreads();
    }
    if (i < NTOT) off[i] = buf[tid] - v;
    if (tid == SB - 1) bsum[blockIdx.x] = buf[tid];
}

__global__ void k_scan2(const int* __restrict__ bsum, int* __restrict__ bbase) {
    __shared__ int b[128];
    int tid = threadIdx.x;
    int v = (tid < NBLK) ? bsum[tid] : 0;
    b[tid] = v;
    __syncthreads();
    for (int s = 1; s < 128; s <<= 1) {
        int t = (tid >= s) ? b[tid - s] : 0;
        __syncthreads();
        b[tid] += t;
        __syncthreads();
    }
    if (tid < NBLK) bbase[tid] = b[tid] - v;
}

// fused: also emit pass-0 raw dval = 0.25*deg (softmax of all-ones logits)
__global__ void k_scan3(int* __restrict__ off, const int* __restrict__ bbase,
                        int* __restrict__ cur, const int* __restrict__ deg,
                        float* __restrict__ dv0) {
    int i = blockIdx.x * blockDim.x + threadIdx.x;
    if (i < NTOT) {
        int o = off[i] + bbase[i >> 10];
        off[i] = o;
        cur[i] = o;
        float d = 0.25f * (float)deg[i];
        ((float4*)dv0)[i] = make_float4(d, d, d, d);
    }
    if (i == 0) off[NTOT] = EDGES;
}

__global__ void k_scatter(const int* __restrict__ h, const int* __restrict__ t,
                          int* __restrict__ cur, int2* __restrict__ et) {
    int e = blockIdx.x * blockDim.x + threadIdx.x;
    if (e >= EDGES) return;
    int hh = h[e];
    int pos = atomicAdd(&cur[hh], 1);
    et[pos] = make_int2(hh, t[e]);
}

// ---- message passing, gather form; dv buffers hold RAW dval (rsqrt applied here) ----
__global__ void k_mp(const unsigned short* __restrict__ egoh, const float* __restrict__ L,
                     const float* __restrict__ dvr, const int* __restrict__ off,
                     const int2* __restrict__ et,
                     unsigned short* __restrict__ fach, float* __restrict__ rhn,
                     unsigned short* __restrict__ tnhOut, float* __restrict__ out,
                     int useL, int writeRhn, int writeTnh, int addOut) {
    int gid = blockIdx.x * blockDim.x + threadIdx.x;
    int wid = gid >> 6;
    int lane = threadIdx.x & 63;
    if (wid >= NTOT) return;
    int f = lane >> 4;
    int beg = off[wid], end = off[wid + 1];
    float dvh = rsqrtf(fmaxf(dvr[wid * 4 + f], 1e-8f));
    float acc = 0.f;
    int j = beg;
    for (; j + 4 <= end; j += 4) {
        int t0 = et[j].y, t1 = et[j + 1].y, t2 = et[j + 2].y, t3 = et[j + 3].y;
        float w0, w1, w2, w3;
        if (useL) {
            w0 = __expf(L[(j + 0) * 4 + f]); w1 = __expf(L[(j + 1) * 4 + f]);
            w2 = __expf(L[(j + 2) * 4 + f]); w3 = __expf(L[(j + 3) * 4 + f]);
        } else {
            w0 = w1 = w2 = w3 = 0.25f;
        }
        float d0 = rsqrtf(fmaxf(dvr[t0 * 4 + f], 1e-8f)),
              d1 = rsqrtf(fmaxf(dvr[t1 * 4 + f], 1e-8f)),
              d2 = rsqrtf(fmaxf(dvr[t2 * 4 + f], 1e-8f)),
              d3 = rsqrtf(fmaxf(dvr[t3 * 4 + f], 1e-8f));
        float g0 = bf2f(egoh[(size_t)t0 * 64 + lane]),
              g1 = bf2f(egoh[(size_t)t1 * 64 + lane]),
              g2 = bf2f(egoh[(size_t)t2 * 64 + lane]),
              g3 = bf2f(egoh[(size_t)t3 * 64 + lane]);
        acc += w0 * d0 * g0 + w1 * d1 * g1 + w2 * d2 * g2 + w3 * d3 * g3;
    }
    for (; j < end; ++j) {
        int t = et[j].y;
        float w = useL ? __expf(L[j * 4 + f]) : 0.25f;
        acc += w * rsqrtf(fmaxf(dvr[t * 4 + f], 1e-8f)) * bf2f(egoh[(size_t)t * 64 + lane]);
    }
    acc *= dvh;
    fach[wid * 64 + lane] = f2bf(acc);
    if (addOut) out[wid * 64 + lane] += acc * (1.0f / 3.0f);
    if (writeRhn || writeTnh) {
        float ss = acc * acc;
        ss += __shfl_xor(ss, 1); ss += __shfl_xor(ss, 2);
        ss += __shfl_xor(ss, 4); ss += __shfl_xor(ss, 8);
        float rr = 1.0f / fmaxf(sqrtf(ss), 1e-12f);
        if (writeRhn && (lane & 15) == 0) rhn[wid * 4 + f] = rr;
        if (writeTnh) tnhOut[wid * 64 + lane] = f2bf(tanhf(acc * rr));
    }
}

// ---- routing update + fused dval via CSR-contiguous segmented reduction ----
// Edges of the same head are contiguous in CSR order: block-local LDS segment
// sums, plain float4 store for interior segments, atomics only at block
// boundaries (~2/block total, NOT 4/edge — round-7 lesson).
__global__ void k_upd(const unsigned short* __restrict__ fach,
                      const unsigned short* __restrict__ tnhh,
                      const float* __restrict__ rhn, const int2* __restrict__ et,
                      float* __restrict__ L, float* __restrict__ dval, int first) {
    __shared__ int   s_h[256];
    __shared__ float s_p[256][4];
    int tid = threadIdx.x;
    int j = blockIdx.x * 256 + tid;
    int h = -1;
    if (j < EDGES) {
        int2 p = et[j];
        h = p.x;
        int t = p.y;
        const uint4* frow = (const uint4*)(fach + (size_t)h * 64);
        const uint4* trow = (const uint4*)(tnhh + (size_t)t * 64);
        float d[4];
#pragma unroll
        for (int f = 0; f < 4; ++f) {
            uint4 a0 = frow[f * 2], a1 = frow[f * 2 + 1];
            uint4 b0 = trow[f * 2], b1 = trow[f * 2 + 1];
            d[f] = dot2(a0.x, b0.x) + dot2(a0.y, b0.y)
                 + dot2(a0.z, b0.z) + dot2(a0.w, b0.w)
                 + dot2(a1.x, b1.x) + dot2(a1.y, b1.y)
                 + dot2(a1.z, b1.z) + dot2(a1.w, b1.w);
        }
        float4 rh = ((const float4*)rhn)[h];
        float lx, ly, lz, lw;
        if (first) { lx = ly = lz = lw = -LOG4; }
        else { float4 l0 = ((const float4*)L)[j]; lx = l0.x; ly = l0.y; lz = l0.z; lw = l0.w; }
        float y0 = lx + rh.x * d[0], y1 = ly + rh.y * d[1],
              y2 = lz + rh.z * d[2], y3 = lw + rh.w * d[3];
        float m = fmaxf(fmaxf(y0, y1), fmaxf(y2, y3));
        float e0 = __expf(y0 - m), e1 = __expf(y1 - m),
              e2 = __expf(y2 - m), e3 = __expf(y3 - m);
        float sum = e0 + e1 + e2 + e3;
        float lse = m + __logf(sum);
        ((float4*)L)[j] = make_float4(y0 - lse, y1 - lse, y2 - lse, y3 - lse);
        float inv = 1.0f / sum;
        s_p[tid][0] = e0 * inv; s_p[tid][1] = e1 * inv;
        s_p[tid][2] = e2 * inv; s_p[tid][3] = e3 * inv;
    }
    s_h[tid] = h;
    __syncthreads();
    if (h == -1) return;
    if (tid > 0 && s_h[tid - 1] == h) return;   // not a segment head
    float a0 = 0.f, a1 = 0.f, a2 = 0.f, a3 = 0.f;
    int k = tid;
    while (k < 256 && s_h[k] == h) {
        a0 += s_p[k][0]; a1 += s_p[k][1]; a2 += s_p[k][2]; a3 += s_p[k][3];
        ++k;
    }
    float* dst = dval + (size_t)h * 4;
    if (tid == 0 || k == 256) {   // may continue in adjacent block -> atomic
        unsafeAtomicAdd(dst + 0, a0);
        unsafeAtomicAdd(dst + 1, a1);
        unsafeAtomicAdd(dst + 2, a2);
        unsafeAtomicAdd(dst + 3, a3);
    } else {                      // fully interior segment -> plain store
        ((float4*)dst)[0] = make_float4(a0, a1, a2, a3);
    }
}

extern "C" void kernel_launch(void* const* d_in, const int* in_sizes, int n_in,
                              void* d_out, int out_size, void* d_ws, size_t ws_size,
                              hipStream_t stream) {
    const void* ue = d_in[0];
    const void* ie = d_in[1];
    const int* hl = (const int*)d_in[2];
    const int* tl = (const int*)d_in[3];
    float* out = (float*)d_out;

    float* ws   = (float*)d_ws;
    float* L    = ws;
    float* dv0  = ws + 4000000;
    float* dv1  = ws + 4320000;
    float* rhn  = ws + 4640000;
    unsigned short* egoA = (unsigned short*)(ws + 4960000);
    unsigned short* egoB = (unsigned short*)(ws + 7520000);
    unsigned short* tnh0 = (unsigned short*)(ws + 10080000);
    unsigned short* tnh1 = (unsigned short*)(ws + 12640000);
    int*   flag = (int*)(ws + 15200000);
    int*   deg  = (int*)(ws + 15200016);
    int*   off  = (int*)(ws + 15280016);
    int*   cur  = (int*)(ws + 15360017);
    int2*  et   = (int2*)(ws + 15440018);
    int*   bsum  = (int*)(ws + 17440018);
    int*   bbase = (int*)(ws + 17440146);

    k_detect<<<1, 256, 0, stream>>>((const unsigned short*)ue, flag);
    k_init<<<20000, 256, 0, stream>>>(ue, ie, flag, egoA, out, tnh0);

    hipMemsetAsync(deg, 0, NTOT * sizeof(int), stream);
    k_deg<<<3907, 256, 0, stream>>>(hl, deg);
    k_scan1<<<NBLK, SB, 0, stream>>>(deg, off, bsum);
    k_scan2<<<1, 128, 0, stream>>>(bsum, bbase);
    k_scan3<<<313, 256, 0, stream>>>(off, bbase, cur, deg, dv0);
    k_scatter<<<3907, 256, 0, stream>>>(hl, tl, cur, et);
    hipMemsetAsync(dv1, 0, NTOT * FAC * sizeof(float), stream);

    // layer 0
    k_mp<<<20000, 256, 0, stream>>>(egoA, L, dv0, off, et, egoB, rhn, tnh1, out,
                                    0, 1, 0, 0);                     // p0
    k_upd<<<3907, 256, 0, stream>>>(egoB, tnh0, rhn, et, L, dv1, 1);
    hipMemsetAsync(dv0, 0, NTOT * FAC * sizeof(float), stream);      // dv0 dead after p0
    k_mp<<<20000, 256, 0, stream>>>(egoA, L, dv1, off, et, egoB, rhn, tnh1, out,
                                    1, 1, 1, 1);                     // p1 (+tnh1 for layer 1)
    k_upd<<<3907, 256, 0, stream>>>(egoB, tnh0, rhn, et, L, dv0, 0);
    hipMemsetAsync(dv1, 0, NTOT * FAC * sizeof(float), stream);      // dv1 dead after p1
    // layer 1 (ego = egoB)
    k_mp<<<20000, 256, 0, stream>>>(egoB, L, dv0, off, et, egoA, rhn, tnh1, out,
                                    1, 1, 0, 0);                     // p2
    k_upd<<<3907, 256, 0, stream>>>(egoA, tnh1, rhn, et, L, dv1, 0);
    k_mp<<<20000, 256, 0, stream>>>(egoB, L, dv1, off, et, egoA, rhn, tnh1, out,
                                    1, 0, 0, 1);                     // p3
}

// Round 11
// 533.413 us; speedup vs baseline: 2.2379x; 1.0116x over previous
//
#include <hip/hip_runtime.h>
#include <hip/hip_bf16.h>

#define N_USER 50000
#define N_ITEM 30000
#define NTOT   80000
#define EMB    64
#define FAC    4
#define EDGES  1000000
#define LOG4   1.3862943611198906f
#define SB     1024
#define NBLK   79   // ceil(80000/1024)

// ws layout (float idx), ~70 MB:
//   P     +0          4,000,000  (softmax probs of A, CSR position order)
//   dv0   +4,000,000    320,000  (dvinv / raw-dval ping)
//   dv1   +4,320,000    320,000  (dvinv / raw-dval pong)
//   rhn   +4,640,000    320,000
//   egoA  +4,960,000  2,560,000  (bf16)
//   egoB  +7,520,000  2,560,000  (bf16)
//   tnh0  +10,080,000 2,560,000  (bf16 layer-0 tanh-normalized)
//   tnh1  +12,640,000 2,560,000  (bf16 layer-1 tanh-normalized)
//   flag  +15,200,000 16
//   deg   +15,200,016 80,000 | off +15,280,016 80,001 | cur +15,360,017 80,000
//   et    +15,440,018 2,000,000 (int2 {h,t} per CSR pos; even idx -> 8B aligned)
//   bsum  +17,440,018 128 | bbase +17,440,146 128

__device__ inline float bf2f(unsigned short u) {
    return __uint_as_float(((unsigned int)u) << 16);
}
__device__ inline unsigned short f2bf(float f) {
    unsigned int x = __float_as_uint(f);
    x += 0x7FFFu + ((x >> 16) & 1u);       // round-to-nearest-even
    return (unsigned short)(x >> 16);
}
__device__ inline float dot2(unsigned int a, unsigned int b) {
    float a0 = __uint_as_float(a << 16), a1 = __uint_as_float(a & 0xFFFF0000u);
    float b0 = __uint_as_float(b << 16), b1 = __uint_as_float(b & 0xFFFF0000u);
    return a0 * b0 + a1 * b1;
}

// ---- input dtype detector (fp32 read-as-bf16 shows inf/NaN bit patterns) ----
__global__ void k_detect(const unsigned short* __restrict__ raw, int* __restrict__ flag) {
    __shared__ int s;
    if (threadIdx.x == 0) s = 0;
    __syncthreads();
    int c = 0;
    for (int i = threadIdx.x; i < 16384; i += 256) {
        unsigned short u = raw[i];
        if ((u & 0x7F80) == 0x7F80) c++;
    }
    atomicAdd(&s, c);
    __syncthreads();
    if (threadIdx.x == 0) *flag = (s > 0) ? 1 : 0;  // 1 => fp32
}

// ---- init: ego(bf16), out accumulator, and layer-0 tnh (fused, wave-per-node) ----
__global__ void k_init(const void* __restrict__ ue, const void* __restrict__ ie,
                       const int* __restrict__ flag,
                       unsigned short* __restrict__ egoh, float* __restrict__ out,
                       unsigned short* __restrict__ tnh0) {
    int gid = blockIdx.x * blockDim.x + threadIdx.x;
    int wid = gid >> 6;
    int lane = threadIdx.x & 63;
    if (wid >= NTOT) return;
    int i = wid * 64 + lane;
    bool isf32 = (*flag != 0);
    float v;
    if (i < N_USER * EMB) {
        v = isf32 ? ((const float*)ue)[i]
                  : __bfloat162float(((const __hip_bfloat16*)ue)[i]);
    } else {
        int j = i - N_USER * EMB;
        v = isf32 ? ((const float*)ie)[j]
                  : __bfloat162float(((const __hip_bfloat16*)ie)[j]);
    }
    egoh[i] = f2bf(v);
    out[i] = v * (1.0f / 3.0f);   // mean-of-3 accumulator, term 1 (exact fp32)
    float ss = v * v;
    ss += __shfl_xor(ss, 1); ss += __shfl_xor(ss, 2);
    ss += __shfl_xor(ss, 4); ss += __shfl_xor(ss, 8);
    float rr = 1.0f / fmaxf(sqrtf(ss), 1e-12f);
    tnh0[i] = f2bf(tanhf(v * rr));
}

// ---- CSR build ----
__global__ void k_deg(const int* __restrict__ h, int* __restrict__ deg) {
    int e = blockIdx.x * blockDim.x + threadIdx.x;
    if (e < EDGES) atomicAdd(&deg[h[e]], 1);
}

__global__ void k_scan1(const int* __restrict__ deg, int* __restrict__ off,
                        int* __restrict__ bsum) {
    __shared__ int buf[SB];
    int tid = threadIdx.x;
    int i = blockIdx.x * SB + tid;
    int v = (i < NTOT) ? deg[i] : 0;
    buf[tid] = v;
    __syncthreads();
    for (int s = 1; s < SB; s <<= 1) {
        int t = (tid >= s) ? buf[tid - s] : 0;
        __syncthreads();
        buf[tid] += t;
        __syncthreads();
    }
    if (i < NTOT) off[i] = buf[tid] - v;
    if (tid == SB - 1) bsum[blockIdx.x] = buf[tid];
}

__global__ void k_scan2(const int* __restrict__ bsum, int* __restrict__ bbase) {
    __shared__ int b[128];
    int tid = threadIdx.x;
    int v = (tid < NBLK) ? bsum[tid] : 0;
    b[tid] = v;
    __syncthreads();
    for (int s = 1; s < 128; s <<= 1) {
        int t = (tid >= s) ? b[tid - s] : 0;
        __syncthreads();
        b[tid] += t;
        __syncthreads();
    }
    if (tid < NBLK) bbase[tid] = b[tid] - v;
}

// fused: also emit pass-0 dvinv = rsqrt(0.25*deg)  (softmax of all-ones logits)
__global__ void k_scan3(int* __restrict__ off, const int* __restrict__ bbase,
                        int* __restrict__ cur, const int* __restrict__ deg,
                        float* __restrict__ dv0) {
    int i = blockIdx.x * blockDim.x + threadIdx.x;
    if (i < NTOT) {
        int o = off[i] + bbase[i >> 10];
        off[i] = o;
        cur[i] = o;
        float d = rsqrtf(fmaxf(0.25f * (float)deg[i], 1e-8f));
        ((float4*)dv0)[i] = make_float4(d, d, d, d);
    }
    if (i == 0) off[NTOT] = EDGES;
}

__global__ void k_scatter(const int* __restrict__ h, const int* __restrict__ t,
                          int* __restrict__ cur, int2* __restrict__ et) {
    int e = blockIdx.x * blockDim.x + threadIdx.x;
    if (e >= EDGES) return;
    int hh = h[e];
    int pos = atomicAdd(&cur[hh], 1);
    et[pos] = make_int2(hh, t[e]);
}

// ---- a: raw dval -> dvinv in place; z: zero for the next accumulation ----
__global__ void k_rsq(float* __restrict__ a, float* __restrict__ z) {
    int i = blockIdx.x * blockDim.x + threadIdx.x;
    if (i >= NTOT * FAC) return;
    a[i] = rsqrtf(fmaxf(a[i], 1e-8f));
    z[i] = 0.f;
}

// ---- message passing, gather form; weight = P * dvinv_h * dvinv_t (no transcendentals) ----
__global__ void k_mp(const unsigned short* __restrict__ egoh, const float* __restrict__ P,
                     const float* __restrict__ dvinv, const int* __restrict__ off,
                     const int2* __restrict__ et,
                     unsigned short* __restrict__ fach, float* __restrict__ rhn,
                     unsigned short* __restrict__ tnhOut, float* __restrict__ out,
                     int useP, int writeRhn, int writeTnh, int addOut) {
    int gid = blockIdx.x * blockDim.x + threadIdx.x;
    int wid = gid >> 6;
    int lane = threadIdx.x & 63;
    if (wid >= NTOT) return;
    int f = lane >> 4;
    int beg = off[wid], end = off[wid + 1];
    float dvh = dvinv[wid * 4 + f];
    float acc = 0.f;
    int j = beg;
    for (; j + 4 <= end; j += 4) {
        int t0 = et[j].y, t1 = et[j + 1].y, t2 = et[j + 2].y, t3 = et[j + 3].y;
        float w0, w1, w2, w3;
        if (useP) {
            w0 = P[(j + 0) * 4 + f]; w1 = P[(j + 1) * 4 + f];
            w2 = P[(j + 2) * 4 + f]; w3 = P[(j + 3) * 4 + f];
        } else {
            w0 = w1 = w2 = w3 = 0.25f;
        }
        float d0 = dvinv[t0 * 4 + f], d1 = dvinv[t1 * 4 + f],
              d2 = dvinv[t2 * 4 + f], d3 = dvinv[t3 * 4 + f];
        float g0 = bf2f(egoh[(size_t)t0 * 64 + lane]),
              g1 = bf2f(egoh[(size_t)t1 * 64 + lane]),
              g2 = bf2f(egoh[(size_t)t2 * 64 + lane]),
              g3 = bf2f(egoh[(size_t)t3 * 64 + lane]);
        acc += w0 * d0 * g0 + w1 * d1 * g1 + w2 * d2 * g2 + w3 * d3 * g3;
    }
    for (; j < end; ++j) {
        int t = et[j].y;
        float w = useP ? P[j * 4 + f] : 0.25f;
        acc += w * dvinv[t * 4 + f] * bf2f(egoh[(size_t)t * 64 + lane]);
    }
    acc *= dvh;
    fach[wid * 64 + lane] = f2bf(acc);
    if (addOut) out[wid * 64 + lane] += acc * (1.0f / 3.0f);
    if (writeRhn || writeTnh) {
        float ss = acc * acc;
        ss += __shfl_xor(ss, 1); ss += __shfl_xor(ss, 2);
        ss += __shfl_xor(ss, 4); ss += __shfl_xor(ss, 8);
        float rr = 1.0f / fmaxf(sqrtf(ss), 1e-12f);
        if (writeRhn && (lane & 15) == 0) rhn[wid * 4 + f] = rr;
        if (writeTnh) tnhOut[wid * 64 + lane] = f2bf(tanhf(acc * rr));
    }
}

// ---- routing update + fused dval via CSR-contiguous segmented reduction ----
// y = log(P_old) + rhn*dot; P_new = softmax(y). Block-local LDS segment sums;
// plain store for interior segments, atomics only at block boundaries.
__global__ void k_upd(const unsigned short* __restrict__ fach,
                      const unsigned short* __restrict__ tnhh,
                      const float* __restrict__ rhn, const int2* __restrict__ et,
                      float* __restrict__ P, float* __restrict__ dval, int first) {
    __shared__ int   s_h[256];
    __shared__ float s_p[256][4];
    int tid = threadIdx.x;
    int j = blockIdx.x * 256 + tid;
    int h = -1;
    if (j < EDGES) {
        int2 p = et[j];
        h = p.x;
        int t = p.y;
        const uint4* frow = (const uint4*)(fach + (size_t)h * 64);
        const uint4* trow = (const uint4*)(tnhh + (size_t)t * 64);
        float d[4];
#pragma unroll
        for (int f = 0; f < 4; ++f) {
            uint4 a0 = frow[f * 2], a1 = frow[f * 2 + 1];
            uint4 b0 = trow[f * 2], b1 = trow[f * 2 + 1];
            d[f] = dot2(a0.x, b0.x) + dot2(a0.y, b0.y)
                 + dot2(a0.z, b0.z) + dot2(a0.w, b0.w)
                 + dot2(a1.x, b1.x) + dot2(a1.y, b1.y)
                 + dot2(a1.z, b1.z) + dot2(a1.w, b1.w);
        }
        float4 rh = ((const float4*)rhn)[h];
        float lx, ly, lz, lw;
        if (first) { lx = ly = lz = lw = -LOG4; }
        else {
            float4 p0 = ((const float4*)P)[j];
            lx = __logf(p0.x); ly = __logf(p0.y);
            lz = __logf(p0.z); lw = __logf(p0.w);
        }
        float y0 = lx + rh.x * d[0], y1 = ly + rh.y * d[1],
              y2 = lz + rh.z * d[2], y3 = lw + rh.w * d[3];
        float m = fmaxf(fmaxf(y0, y1), fmaxf(y2, y3));
        float e0 = __expf(y0 - m), e1 = __expf(y1 - m),
              e2 = __expf(y2 - m), e3 = __expf(y3 - m);
        float inv = 1.0f / (e0 + e1 + e2 + e3);
        float p0n = e0 * inv, p1n = e1 * inv, p2n = e2 * inv, p3n = e3 * inv;
        ((float4*)P)[j] = make_float4(p0n, p1n, p2n, p3n);
        s_p[tid][0] = p0n; s_p[tid][1] = p1n; s_p[tid][2] = p2n; s_p[tid][3] = p3n;
    }
    s_h[tid] = h;
    __syncthreads();
    if (h == -1) return;
    if (tid > 0 && s_h[tid - 1] == h) return;   // not a segment head
    float a0 = 0.f, a1 = 0.f, a2 = 0.f, a3 = 0.f;
    int k = tid;
    while (k < 256 && s_h[k] == h) {
        a0 += s_p[k][0]; a1 += s_p[k][1]; a2 += s_p[k][2]; a3 += s_p[k][3];
        ++k;
    }
    float* dst = dval + (size_t)h * 4;
    if (tid == 0 || k == 256) {   // may continue in adjacent block -> atomic
        unsafeAtomicAdd(dst + 0, a0);
        unsafeAtomicAdd(dst + 1, a1);
        unsafeAtomicAdd(dst + 2, a2);
        unsafeAtomicAdd(dst + 3, a3);
    } else {                      // fully interior segment -> plain store
        ((float4*)dst)[0] = make_float4(a0, a1, a2, a3);
    }
}

extern "C" void kernel_launch(void* const* d_in, const int* in_sizes, int n_in,
                              void* d_out, int out_size, void* d_ws, size_t ws_size,
                              hipStream_t stream) {
    const void* ue = d_in[0];
    const void* ie = d_in[1];
    const int* hl = (const int*)d_in[2];
    const int* tl = (const int*)d_in[3];
    float* out = (float*)d_out;

    float* ws   = (float*)d_ws;
    float* P    = ws;
    float* dv0  = ws + 4000000;
    float* dv1  = ws + 4320000;
    float* rhn  = ws + 4640000;
    unsigned short* egoA = (unsigned short*)(ws + 4960000);
    unsigned short* egoB = (unsigned short*)(ws + 7520000);
    unsigned short* tnh0 = (unsigned short*)(ws + 10080000);
    unsigned short* tnh1 = (unsigned short*)(ws + 12640000);
    int*   flag = (int*)(ws + 15200000);
    int*   deg  = (int*)(ws + 15200016);
    int*   off  = (int*)(ws + 15280016);
    int*   cur  = (int*)(ws + 15360017);
    int2*  et   = (int2*)(ws + 15440018);
    int*   bsum  = (int*)(ws + 17440018);
    int*   bbase = (int*)(ws + 17440146);

    k_detect<<<1, 256, 0, stream>>>((const unsigned short*)ue, flag);
    k_init<<<20000, 256, 0, stream>>>(ue, ie, flag, egoA, out, tnh0);

    hipMemsetAsync(deg, 0, NTOT * sizeof(int), stream);
    k_deg<<<3907, 256, 0, stream>>>(hl, deg);
    k_scan1<<<NBLK, SB, 0, stream>>>(deg, off, bsum);
    k_scan2<<<1, 128, 0, stream>>>(bsum, bbase);
    k_scan3<<<313, 256, 0, stream>>>(off, bbase, cur, deg, dv0);
    k_scatter<<<3907, 256, 0, stream>>>(hl, tl, cur, et);
    hipMemsetAsync(dv1, 0, NTOT * FAC * sizeof(float), stream);

    // layer 0
    k_mp<<<20000, 256, 0, stream>>>(egoA, P, dv0, off, et, egoB, rhn, tnh1, out,
                                    0, 1, 0, 0);                     // p0
    k_upd<<<3907, 256, 0, stream>>>(egoB, tnh0, rhn, et, P, dv1, 1);
    k_rsq<<<1250, 256, 0, stream>>>(dv1, dv0);                        // dv1->dvinv, dv0->0
    k_mp<<<20000, 256, 0, stream>>>(egoA, P, dv1, off, et, egoB, rhn, tnh1, out,
                                    1, 1, 1, 1);                     // p1 (+tnh1 for layer 1)
    k_upd<<<3907, 256, 0, stream>>>(egoB, tnh0, rhn, et, P, dv0, 0);
    k_rsq<<<1250, 256, 0, stream>>>(dv0, dv1);                        // dv0->dvinv, dv1->0
    // layer 1 (ego = egoB)
    k_mp<<<20000, 256, 0, stream>>>(egoB, P, dv0, off, et, egoA, rhn, tnh1, out,
                                    1, 1, 0, 0);                     // p2
    k_upd<<<3907, 256, 0, stream>>>(egoA, tnh1, rhn, et, P, dv1, 0);
    k_rsq<<<1250, 256, 0, stream>>>(dv1, dv0);                        // dv1->dvinv
    k_mp<<<20000, 256, 0, stream>>>(egoB, P, dv1, off, et, egoA, rhn, tnh1, out,
                                    1, 0, 0, 1);                     // p3
}